// Round 17
// baseline (676.943 us; speedup 1.0000x reference)
//
#include <hip/hip_runtime.h>
#include <hip/hip_bf16.h>
#include <math.h>

#define L 4096
#define ECH 128
#define BCH 2
#define NHEAD 4
#define FUSEDC 257
#define CPAD 288   // fused channels padded to multiple of 32 (16B-aligned rows)

typedef __attribute__((ext_vector_type(8))) short bs8;
typedef __attribute__((ext_vector_type(4))) short bs4;
typedef __attribute__((ext_vector_type(4))) float fx4;

// log2(e)/sqrt(32): QK^T scores land directly in exp2 domain
#define SCL 0.25503518f

// round-to-nearest-even f32 -> bf16 bits
static __device__ __forceinline__ short f2bfs(float x) {
  unsigned u = __float_as_uint(x);
  u += 0x7fffu + ((u >> 16) & 1u);
  return (short)(u >> 16);
}

static __device__ __forceinline__ float bf2f(short s) {
  return __uint_as_float((unsigned)(unsigned short)s << 16);
}

static __device__ __forceinline__ float exp2a(float x) {
  float r; asm("v_exp_f32 %0, %1" : "=v"(r) : "v"(x)); return r;
}

static __device__ __forceinline__ unsigned pk2(float lo, float hi) {
  unsigned r; asm("v_cvt_pk_bf16_f32 %0, %1, %2" : "=v"(r) : "v"(lo), "v"(hi)); return r;
}

// ---- merged prep: weights->bf16 + input transpose ----
__global__ void prep_fused(const float* __restrict__ c1w, const float* __restrict__ c2w,
                           const float* __restrict__ wS, const float* __restrict__ wT,
                           const float* __restrict__ woS, const float* __restrict__ woT,
                           const float* __restrict__ sf, const float* __restrict__ tf,
                           short* __restrict__ W1b, short* __restrict__ W2b,
                           short* __restrict__ wSb, short* __restrict__ wTb,
                           short* __restrict__ woSb, short* __restrict__ woTb,
                           short* __restrict__ Xs, short* __restrict__ Xt) {
  __shared__ float t[32][33];
  int bid = blockIdx.x;
  if (bid < 2064) {
    int i = bid * 256 + threadIdx.x;
    if (i < 331776) {
      int ci = i % CPAD; int rest = i / CPAD; int co = rest & 127; int tap = rest >> 7;
      W1b[i] = (ci < FUSEDC) ? f2bfs(c1w[(co * FUSEDC + ci) * 9 + tap]) : (short)0;
    } else if (i < 479232) {
      int j = i - 331776;
      int ci = j & 127; int co = (j >> 7) & 127; int tap = j >> 14;
      W2b[j] = f2bfs(c2w[(co * 128 + ci) * 9 + tap]);
    } else {
      int k = i - 479232; // [0, 49152)
      float s = (k < 16384) ? SCL : 1.0f;
      wSb[k] = f2bfs(wS[k] * s);
      wTb[k] = f2bfs(wT[k] * s);
      if (k < 16384) {
        woSb[k] = f2bfs(woS[k]);
        woTb[k] = f2bfs(woT[k]);
      }
    }
  } else {
    int id = bid - 2064;
    int bx = (id & 127) * 32;
    int by = ((id >> 7) & 3) * 32;
    int z = id >> 9; int b = z & 1; int sel = z >> 1;
    const float* in = sel ? tf : sf;
    short* out = sel ? Xt : Xs;
    int tx = threadIdx.x & 31, ty = threadIdx.x >> 5;
    const float* ip = in + (size_t)b * ECH * L;
    short* op = out + (size_t)b * L * ECH;
#pragma unroll
    for (int r = ty; r < 32; r += 8)
      t[r][tx] = ip[(size_t)(by + r) * L + bx + tx];
    __syncthreads();
#pragma unroll
    for (int r = ty; r < 32; r += 8)
      op[(size_t)(bx + r) * ECH + by + tx] = f2bfs(t[tx][r]);
  }
}

// ---------------- merged QKV GEMM: 6 units ----------------
__global__ void __launch_bounds__(256)
gemm_qkv(const short* __restrict__ Xs, const short* __restrict__ Xt,
         const short* __restrict__ wSb, const short* __restrict__ wTb,
         const float* __restrict__ bS, const float* __restrict__ bT,
         short* __restrict__ qs, short* __restrict__ ks,
         short* __restrict__ qt, short* __restrict__ kt,
         short* __restrict__ vTs, short* __restrict__ vTt) {
  int unit = blockIdx.y;
  const short* X; const short* W; const float* bias; short* out; float scale; int mode;
  switch (unit) {
    case 0: X = Xs; W = wSb;         bias = bS;       out = qs;  scale = SCL; mode = 0; break;
    case 1: X = Xt; W = wSb + 16384; bias = bS + 128; out = ks;  scale = 1.f; mode = 1; break;
    case 2: X = Xt; W = wTb;         bias = bT;       out = qt;  scale = SCL; mode = 0; break;
    case 3: X = Xs; W = wTb + 16384; bias = bT + 128; out = kt;  scale = 1.f; mode = 1; break;
    case 4: X = Xt; W = wSb + 32768; bias = bS + 256; out = vTs; scale = 1.f; mode = 2; break;
    default:X = Xs; W = wTb + 32768; bias = bT + 256; out = vTt; scale = 1.f; mode = 2; break;
  }
  int tid = threadIdx.x;
  int wv = tid >> 6, lane = tid & 63, u = lane >> 4, r = lane & 15;
  int pblk = blockIdx.x * 64 + wv * 16;
  const short* xrow = X + (size_t)(pblk + r) * 128;
  fx4 acc[8] = {};
  if (mode != 2) {
#pragma unroll
    for (int ksx = 0; ksx < 4; ++ksx) {
      int k0 = ksx * 32 + u * 8;
      bs8 a = *(const bs8*)(xrow + k0);
      const short* wp = W + (size_t)r * 128 + k0;
#pragma unroll
      for (int t = 0; t < 8; ++t) {
        bs8 wf = *(const bs8*)(wp + (size_t)t * 16 * 128);
        acc[t] = __builtin_amdgcn_mfma_f32_16x16x32_bf16(a, wf, acc[t], 0, 0, 0);
      }
    }
  } else {
#pragma unroll
    for (int ksx = 0; ksx < 4; ++ksx) {
      int k0 = ksx * 32 + u * 8;
      bs8 xb = *(const bs8*)(xrow + k0);
      const short* wp = W + (size_t)r * 128 + k0;
#pragma unroll
      for (int t = 0; t < 8; ++t) {
        bs8 wf = *(const bs8*)(wp + (size_t)t * 16 * 128);
        acc[t] = __builtin_amdgcn_mfma_f32_16x16x32_bf16(wf, xb, acc[t], 0, 0, 0);
      }
    }
  }
  if (mode == 0) {
#pragma unroll
    for (int t = 0; t < 8; ++t) {
      float bv = bias[t * 16 + r] * scale;
#pragma unroll
      for (int reg = 0; reg < 4; ++reg) {
        int p = pblk + u * 4 + reg;
        out[(size_t)p * 128 + t * 16 + r] = f2bfs(acc[t][reg] + bv);
      }
    }
  } else if (mode == 1) {
#pragma unroll
    for (int t = 0; t < 8; ++t) {
      int och = t * 16 + r, h = och >> 5, d = och & 31;
      float bv = bias[och];
#pragma unroll
      for (int reg = 0; reg < 4; ++reg) {
        int p = pblk + u * 4 + reg;
        int b = p >> 12, pl = p & 4095;
        out[(((size_t)(b * NHEAD + h) * L + pl) << 5) + d] = f2bfs(acc[t][reg] + bv);
      }
    }
  } else {
    int p = pblk + r;
    int b = p >> 12, pl = p & 4095;
#pragma unroll
    for (int t = 0; t < 8; ++t) {
#pragma unroll
      for (int reg = 0; reg < 4; ++reg) {
        int och = t * 16 + u * 4 + reg;
        int h = och >> 5, d = och & 31;
        out[((size_t)(b * NHEAD + h) * 32 + d) * L + pl] = f2bfs(acc[t][reg] + bias[och]);
      }
    }
  }
}

// ---- out-projection with INLINE 8-way split-KV combine -> fusedPM + gnn/pad ------
__global__ void __launch_bounds__(256)
gemm_o(const short* __restrict__ poS0, const short* __restrict__ poS4,
       const short* __restrict__ poT0, const short* __restrict__ poT4,
       const float* __restrict__ pmS, const float* __restrict__ plS,
       const float* __restrict__ pmT, const float* __restrict__ plT,
       const short* __restrict__ woSb, const short* __restrict__ woTb,
       const float* __restrict__ boS, const float* __restrict__ boT,
       const float* __restrict__ gnn, short* __restrict__ fusedPM) {
  int unit = blockIdx.y;
  const short* p0b = unit ? poT0 : poS0;
  const short* p4b = unit ? poT4 : poS4;
  const float* pm = unit ? pmT : pmS;
  const float* pl = unit ? plT : plS;
  const short* W = unit ? woTb : woSb;
  const float* bias = unit ? boT : boS;
  int ochbase = unit ? 128 : 0;
  int tid = threadIdx.x;
  int wv = tid >> 6, lane = tid & 63, u = lane >> 4, r = lane & 15;
  int pblk = blockIdx.x * 64 + wv * 16;
  int p = pblk + r, bb = p >> 12, q = p & 4095;
  fx4 acc[8] = {};
#pragma unroll
  for (int ksx = 0; ksx < 4; ++ksx) {   // ksx == head for this 8-channel slice
    int row = ((bb * NHEAD + ksx) << 12) + q;
    float mi[8], li[8];
#pragma unroll
    for (int i = 0; i < 8; ++i) {
      mi[i] = pm[(i << 15) + row];
      li[i] = pl[(i << 15) + row];
    }
    float mm = mi[0];
#pragma unroll
    for (int i = 1; i < 8; ++i) mm = fmaxf(mm, mi[i]);
    float f[8];
    float den = 0.0f;
#pragma unroll
    for (int i = 0; i < 8; ++i) { f[i] = exp2a(mi[i] - mm); den += li[i] * f[i]; }
    float inv = 1.0f / den;
    int base = (row << 5) + u * 8;
    bs8 v[8];
#pragma unroll
    for (int i = 0; i < 4; ++i) v[i] = *(const bs8*)(p0b + (((size_t)i) << 20) + base);
#pragma unroll
    for (int i = 4; i < 8; ++i) v[i] = *(const bs8*)(p4b + (((size_t)(i - 4)) << 20) + base);
    union { unsigned w32[4]; bs8 vv; } pa;
#pragma unroll
    for (int jj = 0; jj < 4; ++jj) {
      float lo = 0.0f, hi = 0.0f;
#pragma unroll
      for (int i = 0; i < 8; ++i) {
        lo += bf2f(v[i][2 * jj]) * f[i];
        hi += bf2f(v[i][2 * jj + 1]) * f[i];
      }
      pa.w32[jj] = pk2(lo * inv, hi * inv);
    }
    const short* wp = W + (size_t)r * 128 + ksx * 32 + u * 8;
#pragma unroll
    for (int t = 0; t < 8; ++t) {
      bs8 wf = *(const bs8*)(wp + (size_t)t * 16 * 128);
      acc[t] = __builtin_amdgcn_mfma_f32_16x16x32_bf16(pa.vv, wf, acc[t], 0, 0, 0);
    }
  }
#pragma unroll
  for (int t = 0; t < 8; ++t) {
    float bv = bias[t * 16 + r];
#pragma unroll
    for (int reg = 0; reg < 4; ++reg) {
      int pp = pblk + u * 4 + reg;
      fusedPM[(size_t)pp * CPAD + ochbase + t * 16 + r] = f2bfs(acc[t][reg] + bv);
    }
  }
  if (unit == 0) {
    int base = blockIdx.x * 64;
    for (int t2 = tid; t2 < 64 * 32; t2 += 256) {
      int pp = base + (t2 >> 5), j = t2 & 31;
      fusedPM[(size_t)pp * CPAD + 256 + j] = (j == 0) ? f2bfs(gnn[pp]) : (short)0;
    }
  }
}

// ---- split-KV(8) flash attention, 4 q-tiles/wave, shared wave-m, 8 waves/SIMD ----
// grid (16, NHEAD, 32): z = sp*4 + att*2 + b. Each wave: 64 q-rows, 512 keys.
__global__ void __launch_bounds__(256, 8)
flash_attn6(const short* __restrict__ Qs, const short* __restrict__ Ks, const short* __restrict__ Vs,
            const short* __restrict__ Qt, const short* __restrict__ Kt, const short* __restrict__ Vt,
            short* __restrict__ poS0, short* __restrict__ poS4,
            short* __restrict__ poT0, short* __restrict__ poT4,
            float* __restrict__ pmS, float* __restrict__ plS,
            float* __restrict__ pmT, float* __restrict__ plT) {
  int z = blockIdx.z;
  int sp = z >> 2, att = (z >> 1) & 1, b = z & 1;
  const short* Q = att ? Qt : Qs;
  const short* K = att ? Kt : Ks;
  const short* VT = att ? Vt : Vs;
  short* base0 = att ? poT0 : poS0;
  short* base4 = att ? poT4 : poS4;
  short* po = (sp < 4) ? (base0 + (((size_t)sp) << 20))
                       : (base4 + (((size_t)(sp - 4)) << 20));
  float* pm = att ? pmT : pmS;
  float* pl = att ? plT : plS;
  int tid = threadIdx.x;
  int wid = tid >> 6, lane = tid & 63;
  int u = lane >> 4, r = lane & 15;
  int h = blockIdx.y;
  int qt0 = (blockIdx.x << 4) + (wid << 2);
  bs8 qf0 = *(const bs8*)(Q + ((size_t)(b * L + ((qt0 + 0) << 4) + r) * 128 + h * 32 + u * 8));
  bs8 qf1 = *(const bs8*)(Q + ((size_t)(b * L + ((qt0 + 1) << 4) + r) * 128 + h * 32 + u * 8));
  bs8 qf2 = *(const bs8*)(Q + ((size_t)(b * L + ((qt0 + 2) << 4) + r) * 128 + h * 32 + u * 8));
  bs8 qf3 = *(const bs8*)(Q + ((size_t)(b * L + ((qt0 + 3) << 4) + r) * 128 + h * 32 + u * 8));
  const short* Kb = K + (((size_t)(b * NHEAD + h) * L + sp * 512) << 5) + u * 8;
  const short* Vb = VT + ((size_t)(b * NHEAD + h) * 32) * (size_t)L + sp * 512;
  const short* v0p = Vb + (size_t)r * L + (u << 2);
  const short* v1p = Vb + (size_t)(16 + r) * L + (u << 2);
  fx4 o0[4] = {}, o1[4] = {};
  float l[4] = {0.f, 0.f, 0.f, 0.f};
  float m = -1.0e30f;
#pragma unroll 1
  for (int k0 = 0; k0 < 512; k0 += 64) {
    bs8 a0 = *(const bs8*)(Kb + (((size_t)(k0 + r)) << 5));
    bs8 a1 = *(const bs8*)(Kb + (((size_t)(k0 + 16 + r)) << 5));
    bs8 a2 = *(const bs8*)(Kb + (((size_t)(k0 + 32 + r)) << 5));
    bs8 a3 = *(const bs8*)(Kb + (((size_t)(k0 + 48 + r)) << 5));
    bs4 w0 = *(const bs4*)(v0p + k0);
    bs4 w1 = *(const bs4*)(v0p + k0 + 16);
    bs4 w2 = *(const bs4*)(v0p + k0 + 32);
    bs4 w3 = *(const bs4*)(v0p + k0 + 48);
    bs4 w4 = *(const bs4*)(v1p + k0);
    bs4 w5 = *(const bs4*)(v1p + k0 + 16);
    bs4 w6 = *(const bs4*)(v1p + k0 + 32);
    bs4 w7 = *(const bs4*)(v1p + k0 + 48);
    bs8 vb0lo = __builtin_shufflevector(w0, w1, 0, 1, 2, 3, 4, 5, 6, 7);
    bs8 vb0hi = __builtin_shufflevector(w2, w3, 0, 1, 2, 3, 4, 5, 6, 7);
    bs8 vb1lo = __builtin_shufflevector(w4, w5, 0, 1, 2, 3, 4, 5, 6, 7);
    bs8 vb1hi = __builtin_shufflevector(w6, w7, 0, 1, 2, 3, 4, 5, 6, 7);
    fx4 zz = {0.f, 0.f, 0.f, 0.f};
#pragma unroll
    for (int t = 0; t < 4; ++t) {
      bs8 qf = (t == 0) ? qf0 : (t == 1) ? qf1 : (t == 2) ? qf2 : qf3;
      __builtin_amdgcn_s_setprio(1);
      fx4 s0 = __builtin_amdgcn_mfma_f32_16x16x32_bf16(a0, qf, zz, 0, 0, 0);
      fx4 s1 = __builtin_amdgcn_mfma_f32_16x16x32_bf16(a1, qf, zz, 0, 0, 0);
      fx4 s2 = __builtin_amdgcn_mfma_f32_16x16x32_bf16(a2, qf, zz, 0, 0, 0);
      fx4 s3 = __builtin_amdgcn_mfma_f32_16x16x32_bf16(a3, qf, zz, 0, 0, 0);
      __builtin_amdgcn_s_setprio(0);
      float mx = fmaxf(fmaxf(fmaxf(s0[0], s0[1]), fmaxf(s0[2], s0[3])),
                       fmaxf(fmaxf(s1[0], s1[1]), fmaxf(s1[2], s1[3])));
      mx = fmaxf(mx, fmaxf(fmaxf(fmaxf(s2[0], s2[1]), fmaxf(s2[2], s2[3])),
                           fmaxf(fmaxf(s3[0], s3[1]), fmaxf(s3[2], s3[3]))));
      if (!__all(mx <= m + 8.0f)) {
        float gm = fmaxf(mx, __shfl_xor(mx, 1));
        gm = fmaxf(gm, __shfl_xor(gm, 2));
        gm = fmaxf(gm, __shfl_xor(gm, 4));
        gm = fmaxf(gm, __shfl_xor(gm, 8));
        gm = fmaxf(gm, __shfl_xor(gm, 16));
        gm = fmaxf(gm, __shfl_xor(gm, 32));
        float m_new = fmaxf(m, gm);
        float fsc = exp2a(m - m_new);
#pragma unroll
        for (int tt = 0; tt < 4; ++tt) {
          l[tt] *= fsc;
#pragma unroll
          for (int rg = 0; rg < 4; ++rg) { o0[tt][rg] *= fsc; o1[tt][rg] *= fsc; }
        }
        m = m_new;
      }
      fx4 p0, p1, p2, p3;
#pragma unroll
      for (int i = 0; i < 4; ++i) {
        p0[i] = exp2a(s0[i] - m);
        p1[i] = exp2a(s1[i] - m);
        p2[i] = exp2a(s2[i] - m);
        p3[i] = exp2a(s3[i] - m);
      }
      l[t] += ((p0[0] + p0[1]) + (p0[2] + p0[3])) + ((p1[0] + p1[1]) + (p1[2] + p1[3]))
            + ((p2[0] + p2[1]) + (p2[2] + p2[3])) + ((p3[0] + p3[1]) + (p3[2] + p3[3]));
      union { unsigned w32[4]; bs8 v; } plo, phi;
      plo.w32[0] = pk2(p0[0], p0[1]); plo.w32[1] = pk2(p0[2], p0[3]);
      plo.w32[2] = pk2(p1[0], p1[1]); plo.w32[3] = pk2(p1[2], p1[3]);
      phi.w32[0] = pk2(p2[0], p2[1]); phi.w32[1] = pk2(p2[2], p2[3]);
      phi.w32[2] = pk2(p3[0], p3[1]); phi.w32[3] = pk2(p3[2], p3[3]);
      __builtin_amdgcn_s_setprio(1);
      o0[t] = __builtin_amdgcn_mfma_f32_16x16x32_bf16(plo.v, vb0lo, o0[t], 0, 0, 0);
      o0[t] = __builtin_amdgcn_mfma_f32_16x16x32_bf16(phi.v, vb0hi, o0[t], 0, 0, 0);
      o1[t] = __builtin_amdgcn_mfma_f32_16x16x32_bf16(plo.v, vb1lo, o1[t], 0, 0, 0);
      o1[t] = __builtin_amdgcn_mfma_f32_16x16x32_bf16(phi.v, vb1hi, o1[t], 0, 0, 0);
      __builtin_amdgcn_s_setprio(0);
    }
  }
#pragma unroll
  for (int t = 0; t < 4; ++t) {
    float lt = l[t];
    lt += __shfl_xor(lt, 16);
    lt += __shfl_xor(lt, 32);
    int rowb = ((b * NHEAD + h) << 12) + ((qt0 + t) << 4);
    if (lane < 16) {
      pm[(sp << 15) + rowb + r] = m;
      pl[(sp << 15) + rowb + r] = lt;
    }
#pragma unroll
    for (int reg = 0; reg < 4; ++reg) {
      size_t ob = ((size_t)(rowb + (u << 2) + reg) << 5);
      po[ob + r] = f2bfs(o0[t][reg]);
      po[ob + 16 + r] = f2bfs(o1[t][reg]);
    }
  }
}

// ---- conv1 3x3 via MFMA (grid 256,4) + deterministic per-wave stat partials -----
__global__ void __launch_bounds__(128)
conv1_mfma(const short* __restrict__ X, const short* __restrict__ W,
           float* __restrict__ out, float* __restrict__ psum, float* __restrict__ psq) {
  int tid = threadIdx.x;
  int wv = tid >> 6, lane = tid & 63, u = lane >> 4, r = lane & 15;
  int pblk = blockIdx.x * 32 + wv * 16;
  int ybase = blockIdx.y * 32;
  int b = pblk >> 12, y = (pblk & 4095) >> 6, x0 = pblk & 63;
  fx4 acc[2] = {};
  for (int tap = 0; tap < 9; ++tap) {
    int dy = tap / 3 - 1, dx = tap % 3 - 1;
    int yy = y + dy;
    if (yy < 0 || yy > 63) { __syncthreads(); continue; }
    int xx = x0 + r + dx;
    bool valid = (xx >= 0) && (xx <= 63);
    const short* xrow = X + (size_t)((b << 12) + (yy << 6) + x0 + dx + r) * CPAD;
    const short* wtap = W + ((size_t)tap * 128 + ybase + r) * CPAD;
#pragma unroll
    for (int kc = 0; kc < 9; ++kc) {
      int k0 = kc * 32 + u * 8;
      bs8 a = {};
      if (valid) a = *(const bs8*)(xrow + k0);
#pragma unroll
      for (int t = 0; t < 2; ++t) {
        bs8 wf = *(const bs8*)(wtap + (size_t)t * 16 * CPAD + k0);
        acc[t] = __builtin_amdgcn_mfma_f32_16x16x32_bf16(a, wf, acc[t], 0, 0, 0);
      }
    }
    __syncthreads();
  }
#pragma unroll
  for (int t = 0; t < 2; ++t) {
#pragma unroll
    for (int reg = 0; reg < 4; ++reg)
      out[(size_t)(pblk + u * 4 + reg) * 128 + ybase + t * 16 + r] = acc[t][reg];
    float s = (acc[t][0] + acc[t][1]) + (acc[t][2] + acc[t][3]);
    float q = (acc[t][0] * acc[t][0] + acc[t][1] * acc[t][1])
            + (acc[t][2] * acc[t][2] + acc[t][3] * acc[t][3]);
    s += __shfl_xor(s, 16); s += __shfl_xor(s, 32);
    q += __shfl_xor(q, 16); q += __shfl_xor(q, 32);
    if (u == 0) {
      int slot = (ybase + t * 16 + r) * 512 + blockIdx.x * 2 + wv;
      psum[slot] = s;
      psq[slot] = q;
    }
  }
}

// ---- conv2 3x3 via MFMA (grid 256,4) + deterministic per-wave stat partials -----
__global__ void __launch_bounds__(128)
conv2_mfma(const short* __restrict__ X, const short* __restrict__ W,
           float* __restrict__ out, float* __restrict__ psum, float* __restrict__ psq) {
  int tid = threadIdx.x;
  int wv = tid >> 6, lane = tid & 63, u = lane >> 4, r = lane & 15;
  int pblk = blockIdx.x * 32 + wv * 16;
  int ybase = blockIdx.y * 32;
  int b = pblk >> 12, y = (pblk & 4095) >> 6, x0 = pblk & 63;
  fx4 acc[2] = {};
  for (int tap = 0; tap < 9; ++tap) {
    int dy = tap / 3 - 1, dx = tap % 3 - 1;
    int yy = y + dy;
    if (yy < 0 || yy > 63) { __syncthreads(); continue; }
    int xx = x0 + r + dx;
    bool valid = (xx >= 0) && (xx <= 63);
    const short* xrow = X + (size_t)((b << 12) + (yy << 6) + x0 + dx + r) * 128;
    const short* wtap = W + ((size_t)tap * 128 + ybase + r) * 128;
#pragma unroll
    for (int kc = 0; kc < 4; ++kc) {
      int k0 = kc * 32 + u * 8;
      bs8 xb = {};
      if (valid) xb = *(const bs8*)(xrow + k0);
#pragma unroll
      for (int t = 0; t < 2; ++t) {
        bs8 wf = *(const bs8*)(wtap + (size_t)t * 16 * 128 + k0);
        acc[t] = __builtin_amdgcn_mfma_f32_16x16x32_bf16(wf, xb, acc[t], 0, 0, 0);
      }
    }
    __syncthreads();
  }
  int px = y * 64 + x0 + r;
#pragma unroll
  for (int t = 0; t < 2; ++t) {
#pragma unroll
    for (int reg = 0; reg < 4; ++reg) {
      int och = ybase + t * 16 + u * 4 + reg;
      out[((size_t)(b * 128 + och) << 12) + px] = acc[t][reg];
    }
#pragma unroll
    for (int reg = 0; reg < 4; ++reg) {
      float s = acc[t][reg];
      float q = s * s;
      s += __shfl_xor(s, 1); q += __shfl_xor(q, 1);
      s += __shfl_xor(s, 2); q += __shfl_xor(q, 2);
      s += __shfl_xor(s, 4); q += __shfl_xor(q, 4);
      s += __shfl_xor(s, 8); q += __shfl_xor(q, 8);
      if (r == 0) {
        int slot = (ybase + t * 16 + u * 4 + reg) * 512 + blockIdx.x * 2 + wv;
        psum[slot] = s;
        psq[slot] = q;
      }
    }
  }
}

// ---- deterministic stats reduce: 512 partials/channel -> mean, rstd -------------
__global__ void stats_reduce(const float* __restrict__ psum, const float* __restrict__ psq,
                             float* __restrict__ mean, float* __restrict__ rstd) {
  __shared__ float rs[256], rq[256];
  int c = blockIdx.x, tid = threadIdx.x;
  float s = psum[c * 512 + tid] + psum[c * 512 + 256 + tid];
  float q = psq[c * 512 + tid] + psq[c * 512 + 256 + tid];
  rs[tid] = s; rq[tid] = q; __syncthreads();
  for (int st = 128; st > 0; st >>= 1) {
    if (tid < st) { rs[tid] += rs[tid + st]; rq[tid] += rq[tid + st]; }
    __syncthreads();
  }
  if (tid == 0) {
    float m = rs[0] / 8192.0f;
    float v = rq[0] / 8192.0f - m * m;
    mean[c] = m;
    rstd[c] = rsqrtf(v + 1e-5f);
  }
}

// ---------------- BN1 apply + ReLU -> bf16 pm ----------------
__global__ void bnapply_pm(const float* __restrict__ x, const float* __restrict__ mean,
                           const float* __restrict__ rstd, const float* __restrict__ g,
                           const float* __restrict__ bb, short* __restrict__ out) {
  int i = blockIdx.x * 256 + threadIdx.x;
  int c = i & 127;
  float v = x[i];
  out[i] = f2bfs(fmaxf(g[c] * (v - mean[c]) * rstd[c] + bb[c], 0.0f));
}

// ---- fused 1x1 heads (BN2 apply + ReLU folded into the load) ---------------------
__global__ void head_kernel(const float* __restrict__ feat,
                            const float* __restrict__ bmean, const float* __restrict__ brstd,
                            const float* __restrict__ bg, const float* __restrict__ bbias,
                            const float* __restrict__ w1, const float* __restrict__ b1,
                            const float* __restrict__ w2, const float* __restrict__ b2,
                            const float* __restrict__ wo, const float* __restrict__ bo,
                            float* __restrict__ score, float* __restrict__ plog) {
  __shared__ float f[128][64];
  __shared__ float r1[4][64], r2[4][64];
  int by = blockIdx.x; int b = by >> 6, y = by & 63;
  int tid = threadIdx.x;
  int x = tid & 63, g4 = tid >> 6;
  for (int c = g4; c < 128; c += 4) {
    float v = feat[((size_t)(b * 128 + c)) * L + y * 64 + x];
    f[c][x] = fmaxf(bg[c] * (v - bmean[c]) * brstd[c] + bbias[c], 0.0f);
  }
  __syncthreads();
  int cb = g4 * 32;
  float a[32];
#pragma unroll
  for (int i = 0; i < 32; ++i) a[i] = b1[cb + i];
  for (int ci = 0; ci < 128; ++ci) {
    float fv = f[ci][x];
#pragma unroll
    for (int i = 0; i < 32; ++i) a[i] += w1[(size_t)(cb + i) * 128 + ci] * fv;
  }
  float sp = 0.0f;
#pragma unroll
  for (int i = 0; i < 32; ++i) sp += w2[cb + i] * fmaxf(a[i], 0.0f);
  float plp = 0.0f;
#pragma unroll
  for (int i = 0; i < 32; ++i) plp += wo[cb + i] * f[cb + i][x];
  r1[g4][x] = sp; r2[g4][x] = plp;
  __syncthreads();
  if (tid < 64) {
    int xx = tid;
    float s = r1[0][xx] + r1[1][xx] + r1[2][xx] + r1[3][xx] + b2[0];
    float pl = r2[0][xx] + r2[1][xx] + r2[2][xx] + r2[3][xx] + bo[0];
    score[(size_t)b * L + y * 64 + xx] = s;
    plog[(size_t)b * L + y * 64 + xx] = pl;
  }
}

// ---------------- masked softmax + attention maps + bag ----------------
__global__ void finalize_kernel(const float* __restrict__ score, const float* __restrict__ plog,
                                const int* __restrict__ zone, const int* __restrict__ cats,
                                float* __restrict__ maps, float* __restrict__ bag_ws) {
  __shared__ float sc[4096];
  __shared__ float red[256];
  __shared__ int ired[256];
  int b = blockIdx.x, tid = threadIdx.x;
  int cat = cats[b];
  float lmax = -3e38f; int lhas = 0;
  for (int p = tid; p < 4096; p += 256) {
    int z = zone[(size_t)b * 4096 + p];
    int m = (z == cat) && (z > 0);
    float s = m ? score[(size_t)b * 4096 + p] : -1e9f;
    sc[p] = s; lmax = fmaxf(lmax, s); lhas |= m;
  }
  red[tid] = lmax; ired[tid] = lhas; __syncthreads();
  for (int st = 128; st > 0; st >>= 1) {
    if (tid < st) { red[tid] = fmaxf(red[tid], red[tid + st]); ired[tid] |= ired[tid + st]; }
    __syncthreads();
  }
  float gmax = red[0]; int has = ired[0];
  __syncthreads();
  float lsum = 0;
  for (int p = tid; p < 4096; p += 256) {
    float e = __expf(sc[p] - gmax);
    sc[p] = e; lsum += e;
  }
  red[tid] = lsum; __syncthreads();
  for (int st = 128; st > 0; st >>= 1) { if (tid < st) red[tid] += red[tid + st]; __syncthreads(); }
  float inv = 1.0f / red[0];
  __syncthreads();
  float lbag = 0;
  for (int p = tid; p < 4096; p += 256) {
    float w = sc[p] * inv;
    maps[(size_t)b * 4096 + p] = has ? w : 0.0f;
    int z = zone[(size_t)b * 4096 + p];
    if ((z == cat) && (z > 0)) lbag += plog[(size_t)b * 4096 + p] * w;
  }
  red[tid] = lbag; __syncthreads();
  for (int st = 128; st > 0; st >>= 1) { if (tid < st) red[tid] += red[tid + st]; __syncthreads(); }
  if (tid == 0) bag_ws[b] = has ? red[0] : 0.0f;
}

__global__ void loss_kernel(const float* __restrict__ bag_ws, const float* __restrict__ labels,
                            float* __restrict__ out) {
  if (threadIdx.x == 0 && blockIdx.x == 0) {
    float t = 0;
    for (int b = 0; b < BCH; ++b) {
      float x = bag_ws[b];
      float sp = fmaxf(x, 0.0f) + log1pf(expf(-fabsf(x)));
      t += sp - x * labels[b];
    }
    out[0] = t / (float)BCH;
  }
}

extern "C" void kernel_launch(void* const* d_in, const int* in_sizes, int n_in,
                              void* d_out, int out_size, void* d_ws, size_t ws_size,
                              hipStream_t stream) {
  (void)in_sizes; (void)n_in; (void)out_size; (void)ws_size;
  const float* state = (const float*)d_in[0];
  const float* trig  = (const float*)d_in[1];
  const float* gnn   = (const float*)d_in[2];
  const int*   zone  = (const int*)d_in[3];
  const int*   cats  = (const int*)d_in[4];
  const float* labels = (const float*)d_in[5];
  const float* s2t_qkv_w = (const float*)d_in[6];
  const float* s2t_qkv_b = (const float*)d_in[7];
  const float* s2t_out_w = (const float*)d_in[8];
  const float* s2t_out_b = (const float*)d_in[9];
  const float* t2s_qkv_w = (const float*)d_in[10];
  const float* t2s_qkv_b = (const float*)d_in[11];
  const float* t2s_out_w = (const float*)d_in[12];
  const float* t2s_out_b = (const float*)d_in[13];
  const float* fconv1_w = (const float*)d_in[14];
  const float* fbn1_g = (const float*)d_in[15];
  const float* fbn1_b = (const float*)d_in[16];
  const float* fconv2_w = (const float*)d_in[17];
  const float* fbn2_g = (const float*)d_in[18];
  const float* fbn2_b = (const float*)d_in[19];
  const float* outc_w = (const float*)d_in[20];
  const float* outc_b = (const float*)d_in[21];
  const float* attn1_w = (const float*)d_in[22];
  const float* attn1_b = (const float*)d_in[23];
  const float* attn2_w = (const float*)d_in[24];
  const float* attn2_b = (const float*)d_in[25];

  float* ws = (float*)d_ws;
  const size_t NBP = (size_t)BCH * L * 128; // 1,048,576
  size_t o = 0;
  float* c1 = ws + o; o += NBP;            // conv1 out (pm f32); c1||c2 alias poS splits 0-3
  float* c2 = ws + o; o += NBP;            // conv2 out (cm f32)
  float* stats = ws + o; o += 512;         // mean1 rstd1 mean2 rstd2
  float* score = ws + o; o += (size_t)BCH * L;
  float* plog = ws + o; o += (size_t)BCH * L;
  float* bag = ws + o; o += 8;
  short* Xs = (short*)(ws + o); o += NBP / 2;
  short* Xt = (short*)(ws + o); o += NBP / 2;
  short* qsb = (short*)(ws + o); o += NBP / 2;
  short* ksb = (short*)(ws + o); o += NBP / 2;   // head-packed K
  short* qtb = (short*)(ws + o); o += NBP / 2;
  short* ktb = (short*)(ws + o); o += NBP / 2;   // head-packed K
  short* vTsb = (short*)(ws + o); o += NBP / 2;
  short* vTtb = (short*)(ws + o); o += NBP / 2;
  short* fusedPM = (short*)(ws + o); o += (size_t)BCH * L * CPAD / 2;
  short* X2 = (short*)(ws + o); o += NBP / 2;
  short* W1b = (short*)(ws + o); o += (9 * 128 * CPAD) / 2;
  short* W2b = (short*)(ws + o); o += (9 * 128 * 128) / 2;
  short* wSb = (short*)(ws + o); o += 24576;
  short* wTb = (short*)(ws + o); o += 24576;
  short* woSb = (short*)(ws + o); o += 8192;
  short* woTb = (short*)(ws + o); o += 8192;
  short* poT0 = (short*)(ws + o); o += 2 * NBP;  // T splits 0-3 (8 MB)
  short* poT4 = (short*)(ws + o); o += 2 * NBP;  // T splits 4-7 (8 MB)
  short* poS4 = (short*)(ws + o); o += 2 * NBP;  // S splits 4-7 (8 MB)
  float* psum1 = ws + o; o += 128 * 512;
  float* psq1 = ws + o; o += 128 * 512;
  float* psum2 = ws + o; o += 128 * 512;
  float* psq2 = ws + o; o += 128 * 512;
  float* pmT2 = ws + o; o += 8 * 32768;          // pm/pl for T
  float* plT2 = ws + o; o += 8 * 32768;

  // attention partial buffers aliased onto regions dead during attention
  short* poS0 = (short*)c1;           // c1||c2 contiguous: 8 MB = S splits 0-3
  // pm/pl for S live in X2 (dead until bnapply): 16 x 32768 f32 = 2 MB = X2 exactly
  float* pmS = (float*)X2;
  float* plS = pmS + 8 * 32768;
  float* pmT = pmT2;
  float* plT = plT2;

  prep_fused<<<4112, 256, 0, stream>>>(fconv1_w, fconv2_w, s2t_qkv_w, t2s_qkv_w,
                                       s2t_out_w, t2s_out_w, state, trig,
                                       W1b, W2b, wSb, wTb, woSb, woTb, Xs, Xt);

  gemm_qkv<<<dim3(128, 6), 256, 0, stream>>>(Xs, Xt, wSb, wTb, s2t_qkv_b, t2s_qkv_b,
                                             qsb, ksb, qtb, ktb, vTsb, vTtb);

  flash_attn6<<<dim3(16, NHEAD, 32), 256, 0, stream>>>(qsb, ksb, vTsb, qtb, ktb, vTtb,
                                                       poS0, poS4, poT0, poT4,
                                                       pmS, plS, pmT, plT);

  gemm_o<<<dim3(128, 2), 256, 0, stream>>>(poS0, poS4, poT0, poT4,
                                           pmS, plS, pmT, plT,
                                           woSb, woTb, s2t_out_b, t2s_out_b,
                                           gnn, fusedPM);

  conv1_mfma<<<dim3(256, 4), 128, 0, stream>>>(fusedPM, W1b, c1, psum1, psq1);
  stats_reduce<<<128, 256, 0, stream>>>(psum1, psq1, stats, stats + 128);
  bnapply_pm<<<4096, 256, 0, stream>>>(c1, stats, stats + 128, fbn1_g, fbn1_b, X2);

  conv2_mfma<<<dim3(256, 4), 128, 0, stream>>>(X2, W2b, c2, psum2, psq2);
  stats_reduce<<<128, 256, 0, stream>>>(psum2, psq2, stats + 256, stats + 384);

  head_kernel<<<BCH * 64, 256, 0, stream>>>(c2, stats + 256, stats + 384, fbn2_g, fbn2_b,
                                            attn1_w, attn1_b, attn2_w, attn2_b,
                                            outc_w, outc_b, score, plog);

  finalize_kernel<<<BCH, 256, 0, stream>>>(score, plog, zone, cats, (float*)d_out + 1, bag);
  loss_kernel<<<1, 64, 0, stream>>>(bag, labels, (float*)d_out);
}

// Round 18
// 249.264 us; speedup vs baseline: 2.7158x; 2.7158x over previous
//
#include <hip/hip_runtime.h>
#include <hip/hip_bf16.h>
#include <math.h>

#define L 4096
#define ECH 128
#define BCH 2
#define NHEAD 4
#define FUSEDC 257
#define CPAD 288   // fused channels padded to multiple of 32 (16B-aligned rows)

typedef __attribute__((ext_vector_type(8))) short bs8;
typedef __attribute__((ext_vector_type(4))) short bs4;
typedef __attribute__((ext_vector_type(4))) float fx4;

// log2(e)/sqrt(32): QK^T scores land directly in exp2 domain
#define SCL 0.25503518f

// round-to-nearest-even f32 -> bf16 bits
static __device__ __forceinline__ short f2bfs(float x) {
  unsigned u = __float_as_uint(x);
  u += 0x7fffu + ((u >> 16) & 1u);
  return (short)(u >> 16);
}

static __device__ __forceinline__ float bf2f(short s) {
  return __uint_as_float((unsigned)(unsigned short)s << 16);
}

static __device__ __forceinline__ float exp2a(float x) {
  float r; asm("v_exp_f32 %0, %1" : "=v"(r) : "v"(x)); return r;
}

static __device__ __forceinline__ unsigned pk2(float lo, float hi) {
  unsigned r; asm("v_cvt_pk_bf16_f32 %0, %1, %2" : "=v"(r) : "v"(lo), "v"(hi)); return r;
}

// ---- merged prep: weights->bf16 + input transpose ----
__global__ void prep_fused(const float* __restrict__ c1w, const float* __restrict__ c2w,
                           const float* __restrict__ wS, const float* __restrict__ wT,
                           const float* __restrict__ woS, const float* __restrict__ woT,
                           const float* __restrict__ sf, const float* __restrict__ tf,
                           short* __restrict__ W1b, short* __restrict__ W2b,
                           short* __restrict__ wSb, short* __restrict__ wTb,
                           short* __restrict__ woSb, short* __restrict__ woTb,
                           short* __restrict__ Xs, short* __restrict__ Xt) {
  __shared__ float t[32][33];
  int bid = blockIdx.x;
  if (bid < 2064) {
    int i = bid * 256 + threadIdx.x;
    if (i < 331776) {
      int ci = i % CPAD; int rest = i / CPAD; int co = rest & 127; int tap = rest >> 7;
      W1b[i] = (ci < FUSEDC) ? f2bfs(c1w[(co * FUSEDC + ci) * 9 + tap]) : (short)0;
    } else if (i < 479232) {
      int j = i - 331776;
      int ci = j & 127; int co = (j >> 7) & 127; int tap = j >> 14;
      W2b[j] = f2bfs(c2w[(co * 128 + ci) * 9 + tap]);
    } else {
      int k = i - 479232; // [0, 49152)
      float s = (k < 16384) ? SCL : 1.0f;
      wSb[k] = f2bfs(wS[k] * s);
      wTb[k] = f2bfs(wT[k] * s);
      if (k < 16384) {
        woSb[k] = f2bfs(woS[k]);
        woTb[k] = f2bfs(woT[k]);
      }
    }
  } else {
    int id = bid - 2064;
    int bx = (id & 127) * 32;
    int by = ((id >> 7) & 3) * 32;
    int z = id >> 9; int b = z & 1; int sel = z >> 1;
    const float* in = sel ? tf : sf;
    short* out = sel ? Xt : Xs;
    int tx = threadIdx.x & 31, ty = threadIdx.x >> 5;
    const float* ip = in + (size_t)b * ECH * L;
    short* op = out + (size_t)b * L * ECH;
#pragma unroll
    for (int r = ty; r < 32; r += 8)
      t[r][tx] = ip[(size_t)(by + r) * L + bx + tx];
    __syncthreads();
#pragma unroll
    for (int r = ty; r < 32; r += 8)
      op[(size_t)(bx + r) * ECH + by + tx] = f2bfs(t[tx][r]);
  }
}

// ---------------- merged QKV GEMM: 6 units ----------------
__global__ void __launch_bounds__(256)
gemm_qkv(const short* __restrict__ Xs, const short* __restrict__ Xt,
         const short* __restrict__ wSb, const short* __restrict__ wTb,
         const float* __restrict__ bS, const float* __restrict__ bT,
         short* __restrict__ qs, short* __restrict__ ks,
         short* __restrict__ qt, short* __restrict__ kt,
         short* __restrict__ vTs, short* __restrict__ vTt) {
  int unit = blockIdx.y;
  const short* X; const short* W; const float* bias; short* out; float scale; int mode;
  switch (unit) {
    case 0: X = Xs; W = wSb;         bias = bS;       out = qs;  scale = SCL; mode = 0; break;
    case 1: X = Xt; W = wSb + 16384; bias = bS + 128; out = ks;  scale = 1.f; mode = 1; break;
    case 2: X = Xt; W = wTb;         bias = bT;       out = qt;  scale = SCL; mode = 0; break;
    case 3: X = Xs; W = wTb + 16384; bias = bT + 128; out = kt;  scale = 1.f; mode = 1; break;
    case 4: X = Xt; W = wSb + 32768; bias = bS + 256; out = vTs; scale = 1.f; mode = 2; break;
    default:X = Xs; W = wTb + 32768; bias = bT + 256; out = vTt; scale = 1.f; mode = 2; break;
  }
  int tid = threadIdx.x;
  int wv = tid >> 6, lane = tid & 63, u = lane >> 4, r = lane & 15;
  int pblk = blockIdx.x * 64 + wv * 16;
  const short* xrow = X + (size_t)(pblk + r) * 128;
  fx4 acc[8] = {};
  if (mode != 2) {
#pragma unroll
    for (int ksx = 0; ksx < 4; ++ksx) {
      int k0 = ksx * 32 + u * 8;
      bs8 a = *(const bs8*)(xrow + k0);
      const short* wp = W + (size_t)r * 128 + k0;
#pragma unroll
      for (int t = 0; t < 8; ++t) {
        bs8 wf = *(const bs8*)(wp + (size_t)t * 16 * 128);
        acc[t] = __builtin_amdgcn_mfma_f32_16x16x32_bf16(a, wf, acc[t], 0, 0, 0);
      }
    }
  } else {
#pragma unroll
    for (int ksx = 0; ksx < 4; ++ksx) {
      int k0 = ksx * 32 + u * 8;
      bs8 xb = *(const bs8*)(xrow + k0);
      const short* wp = W + (size_t)r * 128 + k0;
#pragma unroll
      for (int t = 0; t < 8; ++t) {
        bs8 wf = *(const bs8*)(wp + (size_t)t * 16 * 128);
        acc[t] = __builtin_amdgcn_mfma_f32_16x16x32_bf16(wf, xb, acc[t], 0, 0, 0);
      }
    }
  }
  if (mode == 0) {
#pragma unroll
    for (int t = 0; t < 8; ++t) {
      float bv = bias[t * 16 + r] * scale;
#pragma unroll
      for (int reg = 0; reg < 4; ++reg) {
        int p = pblk + u * 4 + reg;
        out[(size_t)p * 128 + t * 16 + r] = f2bfs(acc[t][reg] + bv);
      }
    }
  } else if (mode == 1) {
#pragma unroll
    for (int t = 0; t < 8; ++t) {
      int och = t * 16 + r, h = och >> 5, d = och & 31;
      float bv = bias[och];
#pragma unroll
      for (int reg = 0; reg < 4; ++reg) {
        int p = pblk + u * 4 + reg;
        int b = p >> 12, pl = p & 4095;
        out[(((size_t)(b * NHEAD + h) * L + pl) << 5) + d] = f2bfs(acc[t][reg] + bv);
      }
    }
  } else {
    int p = pblk + r;
    int b = p >> 12, pl = p & 4095;
#pragma unroll
    for (int t = 0; t < 8; ++t) {
#pragma unroll
      for (int reg = 0; reg < 4; ++reg) {
        int och = t * 16 + u * 4 + reg;
        int h = och >> 5, d = och & 31;
        out[((size_t)(b * NHEAD + h) * 32 + d) * L + pl] = f2bfs(acc[t][reg] + bias[och]);
      }
    }
  }
}

// ---- out-projection with INLINE split-KV combine -> fusedPM + gnn/pad ------------
// A-fragment built on the fly from 4 unnormalized partials + per-row m/l.
__global__ void __launch_bounds__(256)
gemm_o(const short* __restrict__ poS, const float* __restrict__ pmS, const float* __restrict__ plS,
       const short* __restrict__ poT, const float* __restrict__ pmT, const float* __restrict__ plT,
       const short* __restrict__ woSb, const short* __restrict__ woTb,
       const float* __restrict__ boS, const float* __restrict__ boT,
       const float* __restrict__ gnn, short* __restrict__ fusedPM) {
  int unit = blockIdx.y;
  const short* po = unit ? poT : poS;
  const float* pm = unit ? pmT : pmS;
  const float* pl = unit ? plT : plS;
  const short* W = unit ? woTb : woSb;
  const float* bias = unit ? boT : boS;
  int ochbase = unit ? 128 : 0;
  int tid = threadIdx.x;
  int wv = tid >> 6, lane = tid & 63, u = lane >> 4, r = lane & 15;
  int pblk = blockIdx.x * 64 + wv * 16;
  int p = pblk + r, bb = p >> 12, q = p & 4095;
  fx4 acc[8] = {};
#pragma unroll
  for (int ksx = 0; ksx < 4; ++ksx) {   // ksx == head for this 8-channel slice
    int row = ((bb * NHEAD + ksx) << 12) + q;
    float m0 = pm[row], m1 = pm[32768 + row];
    float m2 = pm[65536 + row], m3 = pm[98304 + row];
    float l0 = pl[row], l1 = pl[32768 + row];
    float l2 = pl[65536 + row], l3 = pl[98304 + row];
    float mm = fmaxf(fmaxf(m0, m1), fmaxf(m2, m3));
    float f0 = exp2a(m0 - mm), f1 = exp2a(m1 - mm);
    float f2 = exp2a(m2 - mm), f3 = exp2a(m3 - mm);
    float inv = 1.0f / (l0 * f0 + l1 * f1 + l2 * f2 + l3 * f3);
    int base = (row << 5) + u * 8;
    bs8 v0 = *(const bs8*)(po + base);
    bs8 v1 = *(const bs8*)(po + (1 << 20) + base);
    bs8 v2 = *(const bs8*)(po + (2 << 20) + base);
    bs8 v3 = *(const bs8*)(po + (3 << 20) + base);
    union { unsigned w32[4]; bs8 v; } pa;
#pragma unroll
    for (int jj = 0; jj < 4; ++jj) {
      float lo = (bf2f(v0[2 * jj]) * f0 + bf2f(v1[2 * jj]) * f1
                + bf2f(v2[2 * jj]) * f2 + bf2f(v3[2 * jj]) * f3) * inv;
      float hi = (bf2f(v0[2 * jj + 1]) * f0 + bf2f(v1[2 * jj + 1]) * f1
                + bf2f(v2[2 * jj + 1]) * f2 + bf2f(v3[2 * jj + 1]) * f3) * inv;
      pa.w32[jj] = pk2(lo, hi);
    }
    const short* wp = W + (size_t)r * 128 + ksx * 32 + u * 8;
#pragma unroll
    for (int t = 0; t < 8; ++t) {
      bs8 wf = *(const bs8*)(wp + (size_t)t * 16 * 128);
      acc[t] = __builtin_amdgcn_mfma_f32_16x16x32_bf16(pa.v, wf, acc[t], 0, 0, 0);
    }
  }
#pragma unroll
  for (int t = 0; t < 8; ++t) {
    float bv = bias[t * 16 + r];
#pragma unroll
    for (int reg = 0; reg < 4; ++reg) {
      int pp = pblk + u * 4 + reg;
      fusedPM[(size_t)pp * CPAD + ochbase + t * 16 + r] = f2bfs(acc[t][reg] + bv);
    }
  }
  if (unit == 0) {
    int base = blockIdx.x * 64;
    for (int t2 = tid; t2 < 64 * 32; t2 += 256) {
      int pp = base + (t2 >> 5), j = t2 & 31;
      fusedPM[(size_t)pp * CPAD + 256 + j] = (j == 0) ? f2bfs(gnn[pp]) : (short)0;
    }
  }
}

// ---------------- split-KV(4) flash attention, 4 q-tiles/wave, shared wave-m ------
__global__ void __launch_bounds__(256, 4)
flash_attn6(const short* __restrict__ Qs, const short* __restrict__ Ks, const short* __restrict__ Vs,
            const short* __restrict__ Qt, const short* __restrict__ Kt, const short* __restrict__ Vt,
            short* __restrict__ poS, short* __restrict__ poT,
            float* __restrict__ pmS, float* __restrict__ plS,
            float* __restrict__ pmT, float* __restrict__ plT) {
  int z = blockIdx.z;
  int sp = z >> 2, att = (z >> 1) & 1, b = z & 1;
  const short* Q = att ? Qt : Qs;
  const short* K = att ? Kt : Ks;
  const short* VT = att ? Vt : Vs;
  short* po = att ? poT : poS;
  float* pm = att ? pmT : pmS;
  float* pl = att ? plT : plS;
  int tid = threadIdx.x;
  int wid = tid >> 6, lane = tid & 63;
  int u = lane >> 4, r = lane & 15;
  int h = blockIdx.y;
  int qt0 = (blockIdx.x << 4) + (wid << 2);
  bs8 qf0 = *(const bs8*)(Q + ((size_t)(b * L + ((qt0 + 0) << 4) + r) * 128 + h * 32 + u * 8));
  bs8 qf1 = *(const bs8*)(Q + ((size_t)(b * L + ((qt0 + 1) << 4) + r) * 128 + h * 32 + u * 8));
  bs8 qf2 = *(const bs8*)(Q + ((size_t)(b * L + ((qt0 + 2) << 4) + r) * 128 + h * 32 + u * 8));
  bs8 qf3 = *(const bs8*)(Q + ((size_t)(b * L + ((qt0 + 3) << 4) + r) * 128 + h * 32 + u * 8));
  const short* Kb = K + (((size_t)(b * NHEAD + h) * L + sp * 1024) << 5) + u * 8;
  const short* Vb = VT + ((size_t)(b * NHEAD + h) * 32) * (size_t)L + sp * 1024;
  const short* v0p = Vb + (size_t)r * L + (u << 2);
  const short* v1p = Vb + (size_t)(16 + r) * L + (u << 2);
  fx4 o0[4] = {}, o1[4] = {};
  float l[4] = {0.f, 0.f, 0.f, 0.f};
  float m = -1.0e30f;
#pragma unroll 1
  for (int k0 = 0; k0 < 1024; k0 += 64) {
    bs8 a0 = *(const bs8*)(Kb + (((size_t)(k0 + r)) << 5));
    bs8 a1 = *(const bs8*)(Kb + (((size_t)(k0 + 16 + r)) << 5));
    bs8 a2 = *(const bs8*)(Kb + (((size_t)(k0 + 32 + r)) << 5));
    bs8 a3 = *(const bs8*)(Kb + (((size_t)(k0 + 48 + r)) << 5));
    bs4 w0 = *(const bs4*)(v0p + k0);
    bs4 w1 = *(const bs4*)(v0p + k0 + 16);
    bs4 w2 = *(const bs4*)(v0p + k0 + 32);
    bs4 w3 = *(const bs4*)(v0p + k0 + 48);
    bs4 w4 = *(const bs4*)(v1p + k0);
    bs4 w5 = *(const bs4*)(v1p + k0 + 16);
    bs4 w6 = *(const bs4*)(v1p + k0 + 32);
    bs4 w7 = *(const bs4*)(v1p + k0 + 48);
    bs8 vb0lo = __builtin_shufflevector(w0, w1, 0, 1, 2, 3, 4, 5, 6, 7);
    bs8 vb0hi = __builtin_shufflevector(w2, w3, 0, 1, 2, 3, 4, 5, 6, 7);
    bs8 vb1lo = __builtin_shufflevector(w4, w5, 0, 1, 2, 3, 4, 5, 6, 7);
    bs8 vb1hi = __builtin_shufflevector(w6, w7, 0, 1, 2, 3, 4, 5, 6, 7);
    fx4 zz = {0.f, 0.f, 0.f, 0.f};
#pragma unroll
    for (int t = 0; t < 4; ++t) {
      bs8 qf = (t == 0) ? qf0 : (t == 1) ? qf1 : (t == 2) ? qf2 : qf3;
      __builtin_amdgcn_s_setprio(1);
      fx4 s0 = __builtin_amdgcn_mfma_f32_16x16x32_bf16(a0, qf, zz, 0, 0, 0);
      fx4 s1 = __builtin_amdgcn_mfma_f32_16x16x32_bf16(a1, qf, zz, 0, 0, 0);
      fx4 s2 = __builtin_amdgcn_mfma_f32_16x16x32_bf16(a2, qf, zz, 0, 0, 0);
      fx4 s3 = __builtin_amdgcn_mfma_f32_16x16x32_bf16(a3, qf, zz, 0, 0, 0);
      __builtin_amdgcn_s_setprio(0);
      float mx = fmaxf(fmaxf(fmaxf(s0[0], s0[1]), fmaxf(s0[2], s0[3])),
                       fmaxf(fmaxf(s1[0], s1[1]), fmaxf(s1[2], s1[3])));
      mx = fmaxf(mx, fmaxf(fmaxf(fmaxf(s2[0], s2[1]), fmaxf(s2[2], s2[3])),
                           fmaxf(fmaxf(s3[0], s3[1]), fmaxf(s3[2], s3[3]))));
      if (!__all(mx <= m + 8.0f)) {
        float gm = fmaxf(mx, __shfl_xor(mx, 1));
        gm = fmaxf(gm, __shfl_xor(gm, 2));
        gm = fmaxf(gm, __shfl_xor(gm, 4));
        gm = fmaxf(gm, __shfl_xor(gm, 8));
        gm = fmaxf(gm, __shfl_xor(gm, 16));
        gm = fmaxf(gm, __shfl_xor(gm, 32));
        float m_new = fmaxf(m, gm);
        float fsc = exp2a(m - m_new);
#pragma unroll
        for (int tt = 0; tt < 4; ++tt) {
          l[tt] *= fsc;
#pragma unroll
          for (int rg = 0; rg < 4; ++rg) { o0[tt][rg] *= fsc; o1[tt][rg] *= fsc; }
        }
        m = m_new;
      }
      fx4 p0, p1, p2, p3;
#pragma unroll
      for (int i = 0; i < 4; ++i) {
        p0[i] = exp2a(s0[i] - m);
        p1[i] = exp2a(s1[i] - m);
        p2[i] = exp2a(s2[i] - m);
        p3[i] = exp2a(s3[i] - m);
      }
      l[t] += ((p0[0] + p0[1]) + (p0[2] + p0[3])) + ((p1[0] + p1[1]) + (p1[2] + p1[3]))
            + ((p2[0] + p2[1]) + (p2[2] + p2[3])) + ((p3[0] + p3[1]) + (p3[2] + p3[3]));
      union { unsigned w32[4]; bs8 v; } plo, phi;
      plo.w32[0] = pk2(p0[0], p0[1]); plo.w32[1] = pk2(p0[2], p0[3]);
      plo.w32[2] = pk2(p1[0], p1[1]); plo.w32[3] = pk2(p1[2], p1[3]);
      phi.w32[0] = pk2(p2[0], p2[1]); phi.w32[1] = pk2(p2[2], p2[3]);
      phi.w32[2] = pk2(p3[0], p3[1]); phi.w32[3] = pk2(p3[2], p3[3]);
      __builtin_amdgcn_s_setprio(1);
      o0[t] = __builtin_amdgcn_mfma_f32_16x16x32_bf16(plo.v, vb0lo, o0[t], 0, 0, 0);
      o0[t] = __builtin_amdgcn_mfma_f32_16x16x32_bf16(phi.v, vb0hi, o0[t], 0, 0, 0);
      o1[t] = __builtin_amdgcn_mfma_f32_16x16x32_bf16(plo.v, vb1lo, o1[t], 0, 0, 0);
      o1[t] = __builtin_amdgcn_mfma_f32_16x16x32_bf16(phi.v, vb1hi, o1[t], 0, 0, 0);
      __builtin_amdgcn_s_setprio(0);
    }
  }
#pragma unroll
  for (int t = 0; t < 4; ++t) {
    float lt = l[t];
    lt += __shfl_xor(lt, 16);
    lt += __shfl_xor(lt, 32);
    int rowb = ((b * NHEAD + h) << 12) + ((qt0 + t) << 4);
    if (lane < 16) {
      pm[(sp << 15) + rowb + r] = m;
      pl[(sp << 15) + rowb + r] = lt;
    }
#pragma unroll
    for (int reg = 0; reg < 4; ++reg) {
      size_t ob = ((size_t)sp << 20) + ((size_t)(rowb + (u << 2) + reg) << 5);
      po[ob + r] = f2bfs(o0[t][reg]);
      po[ob + 16 + r] = f2bfs(o1[t][reg]);
    }
  }
}

// ---- conv1 3x3 via MFMA (grid 256,4) + deterministic per-wave stat partials -----
__global__ void __launch_bounds__(128)
conv1_mfma(const short* __restrict__ X, const short* __restrict__ W,
           float* __restrict__ out, float* __restrict__ psum, float* __restrict__ psq) {
  int tid = threadIdx.x;
  int wv = tid >> 6, lane = tid & 63, u = lane >> 4, r = lane & 15;
  int pblk = blockIdx.x * 32 + wv * 16;
  int ybase = blockIdx.y * 32;
  int b = pblk >> 12, y = (pblk & 4095) >> 6, x0 = pblk & 63;
  fx4 acc[2] = {};
  for (int tap = 0; tap < 9; ++tap) {
    int dy = tap / 3 - 1, dx = tap % 3 - 1;
    int yy = y + dy;
    if (yy < 0 || yy > 63) { __syncthreads(); continue; }
    int xx = x0 + r + dx;
    bool valid = (xx >= 0) && (xx <= 63);
    const short* xrow = X + (size_t)((b << 12) + (yy << 6) + x0 + dx + r) * CPAD;
    const short* wtap = W + ((size_t)tap * 128 + ybase + r) * CPAD;
#pragma unroll
    for (int kc = 0; kc < 9; ++kc) {
      int k0 = kc * 32 + u * 8;
      bs8 a = {};
      if (valid) a = *(const bs8*)(xrow + k0);
#pragma unroll
      for (int t = 0; t < 2; ++t) {
        bs8 wf = *(const bs8*)(wtap + (size_t)t * 16 * CPAD + k0);
        acc[t] = __builtin_amdgcn_mfma_f32_16x16x32_bf16(a, wf, acc[t], 0, 0, 0);
      }
    }
    __syncthreads();
  }
#pragma unroll
  for (int t = 0; t < 2; ++t) {
#pragma unroll
    for (int reg = 0; reg < 4; ++reg)
      out[(size_t)(pblk + u * 4 + reg) * 128 + ybase + t * 16 + r] = acc[t][reg];
    float s = (acc[t][0] + acc[t][1]) + (acc[t][2] + acc[t][3]);
    float q = (acc[t][0] * acc[t][0] + acc[t][1] * acc[t][1])
            + (acc[t][2] * acc[t][2] + acc[t][3] * acc[t][3]);
    s += __shfl_xor(s, 16); s += __shfl_xor(s, 32);
    q += __shfl_xor(q, 16); q += __shfl_xor(q, 32);
    if (u == 0) {
      int slot = (ybase + t * 16 + r) * 512 + blockIdx.x * 2 + wv;
      psum[slot] = s;
      psq[slot] = q;
    }
  }
}

// ---- conv2 3x3 via MFMA (grid 256,4) + deterministic per-wave stat partials -----
__global__ void __launch_bounds__(128)
conv2_mfma(const short* __restrict__ X, const short* __restrict__ W,
           float* __restrict__ out, float* __restrict__ psum, float* __restrict__ psq) {
  int tid = threadIdx.x;
  int wv = tid >> 6, lane = tid & 63, u = lane >> 4, r = lane & 15;
  int pblk = blockIdx.x * 32 + wv * 16;
  int ybase = blockIdx.y * 32;
  int b = pblk >> 12, y = (pblk & 4095) >> 6, x0 = pblk & 63;
  fx4 acc[2] = {};
  for (int tap = 0; tap < 9; ++tap) {
    int dy = tap / 3 - 1, dx = tap % 3 - 1;
    int yy = y + dy;
    if (yy < 0 || yy > 63) { __syncthreads(); continue; }
    int xx = x0 + r + dx;
    bool valid = (xx >= 0) && (xx <= 63);
    const short* xrow = X + (size_t)((b << 12) + (yy << 6) + x0 + dx + r) * 128;
    const short* wtap = W + ((size_t)tap * 128 + ybase + r) * 128;
#pragma unroll
    for (int kc = 0; kc < 4; ++kc) {
      int k0 = kc * 32 + u * 8;
      bs8 xb = {};
      if (valid) xb = *(const bs8*)(xrow + k0);
#pragma unroll
      for (int t = 0; t < 2; ++t) {
        bs8 wf = *(const bs8*)(wtap + (size_t)t * 16 * 128 + k0);
        acc[t] = __builtin_amdgcn_mfma_f32_16x16x32_bf16(wf, xb, acc[t], 0, 0, 0);
      }
    }
    __syncthreads();
  }
  int px = y * 64 + x0 + r;
#pragma unroll
  for (int t = 0; t < 2; ++t) {
#pragma unroll
    for (int reg = 0; reg < 4; ++reg) {
      int och = ybase + t * 16 + u * 4 + reg;
      out[((size_t)(b * 128 + och) << 12) + px] = acc[t][reg];
    }
#pragma unroll
    for (int reg = 0; reg < 4; ++reg) {
      float s = acc[t][reg];
      float q = s * s;
      s += __shfl_xor(s, 1); q += __shfl_xor(q, 1);
      s += __shfl_xor(s, 2); q += __shfl_xor(q, 2);
      s += __shfl_xor(s, 4); q += __shfl_xor(q, 4);
      s += __shfl_xor(s, 8); q += __shfl_xor(q, 8);
      if (r == 0) {
        int slot = (ybase + t * 16 + u * 4 + reg) * 512 + blockIdx.x * 2 + wv;
        psum[slot] = s;
        psq[slot] = q;
      }
    }
  }
}

// ---- deterministic stats reduce: 512 partials/channel -> mean, rstd -------------
__global__ void stats_reduce(const float* __restrict__ psum, const float* __restrict__ psq,
                             float* __restrict__ mean, float* __restrict__ rstd) {
  __shared__ float rs[256], rq[256];
  int c = blockIdx.x, tid = threadIdx.x;
  float s = psum[c * 512 + tid] + psum[c * 512 + 256 + tid];
  float q = psq[c * 512 + tid] + psq[c * 512 + 256 + tid];
  rs[tid] = s; rq[tid] = q; __syncthreads();
  for (int st = 128; st > 0; st >>= 1) {
    if (tid < st) { rs[tid] += rs[tid + st]; rq[tid] += rq[tid + st]; }
    __syncthreads();
  }
  if (tid == 0) {
    float m = rs[0] / 8192.0f;
    float v = rq[0] / 8192.0f - m * m;
    mean[c] = m;
    rstd[c] = rsqrtf(v + 1e-5f);
  }
}

// ---------------- BN1 apply + ReLU -> bf16 pm ----------------
__global__ void bnapply_pm(const float* __restrict__ x, const float* __restrict__ mean,
                           const float* __restrict__ rstd, const float* __restrict__ g,
                           const float* __restrict__ bb, short* __restrict__ out) {
  int i = blockIdx.x * 256 + threadIdx.x;
  int c = i & 127;
  float v = x[i];
  out[i] = f2bfs(fmaxf(g[c] * (v - mean[c]) * rstd[c] + bb[c], 0.0f));
}

// ---- fused 1x1 heads (BN2 apply + ReLU folded into the load) ---------------------
__global__ void head_kernel(const float* __restrict__ feat,
                            const float* __restrict__ bmean, const float* __restrict__ brstd,
                            const float* __restrict__ bg, const float* __restrict__ bbias,
                            const float* __restrict__ w1, const float* __restrict__ b1,
                            const float* __restrict__ w2, const float* __restrict__ b2,
                            const float* __restrict__ wo, const float* __restrict__ bo,
                            float* __restrict__ score, float* __restrict__ plog) {
  __shared__ float f[128][64];
  __shared__ float r1[4][64], r2[4][64];
  int by = blockIdx.x; int b = by >> 6, y = by & 63;
  int tid = threadIdx.x;
  int x = tid & 63, g4 = tid >> 6;
  for (int c = g4; c < 128; c += 4) {
    float v = feat[((size_t)(b * 128 + c)) * L + y * 64 + x];
    f[c][x] = fmaxf(bg[c] * (v - bmean[c]) * brstd[c] + bbias[c], 0.0f);
  }
  __syncthreads();
  int cb = g4 * 32;
  float a[32];
#pragma unroll
  for (int i = 0; i < 32; ++i) a[i] = b1[cb + i];
  for (int ci = 0; ci < 128; ++ci) {
    float fv = f[ci][x];
#pragma unroll
    for (int i = 0; i < 32; ++i) a[i] += w1[(size_t)(cb + i) * 128 + ci] * fv;
  }
  float sp = 0.0f;
#pragma unroll
  for (int i = 0; i < 32; ++i) sp += w2[cb + i] * fmaxf(a[i], 0.0f);
  float plp = 0.0f;
#pragma unroll
  for (int i = 0; i < 32; ++i) plp += wo[cb + i] * f[cb + i][x];
  r1[g4][x] = sp; r2[g4][x] = plp;
  __syncthreads();
  if (tid < 64) {
    int xx = tid;
    float s = r1[0][xx] + r1[1][xx] + r1[2][xx] + r1[3][xx] + b2[0];
    float pl = r2[0][xx] + r2[1][xx] + r2[2][xx] + r2[3][xx] + bo[0];
    score[(size_t)b * L + y * 64 + xx] = s;
    plog[(size_t)b * L + y * 64 + xx] = pl;
  }
}

// ---------------- masked softmax + attention maps + bag ----------------
__global__ void finalize_kernel(const float* __restrict__ score, const float* __restrict__ plog,
                                const int* __restrict__ zone, const int* __restrict__ cats,
                                float* __restrict__ maps, float* __restrict__ bag_ws) {
  __shared__ float sc[4096];
  __shared__ float red[256];
  __shared__ int ired[256];
  int b = blockIdx.x, tid = threadIdx.x;
  int cat = cats[b];
  float lmax = -3e38f; int lhas = 0;
  for (int p = tid; p < 4096; p += 256) {
    int z = zone[(size_t)b * 4096 + p];
    int m = (z == cat) && (z > 0);
    float s = m ? score[(size_t)b * 4096 + p] : -1e9f;
    sc[p] = s; lmax = fmaxf(lmax, s); lhas |= m;
  }
  red[tid] = lmax; ired[tid] = lhas; __syncthreads();
  for (int st = 128; st > 0; st >>= 1) {
    if (tid < st) { red[tid] = fmaxf(red[tid], red[tid + st]); ired[tid] |= ired[tid + st]; }
    __syncthreads();
  }
  float gmax = red[0]; int has = ired[0];
  __syncthreads();
  float lsum = 0;
  for (int p = tid; p < 4096; p += 256) {
    float e = __expf(sc[p] - gmax);
    sc[p] = e; lsum += e;
  }
  red[tid] = lsum; __syncthreads();
  for (int st = 128; st > 0; st >>= 1) { if (tid < st) red[tid] += red[tid + st]; __syncthreads(); }
  float inv = 1.0f / red[0];
  __syncthreads();
  float lbag = 0;
  for (int p = tid; p < 4096; p += 256) {
    float w = sc[p] * inv;
    maps[(size_t)b * 4096 + p] = has ? w : 0.0f;
    int z = zone[(size_t)b * 4096 + p];
    if ((z == cat) && (z > 0)) lbag += plog[(size_t)b * 4096 + p] * w;
  }
  red[tid] = lbag; __syncthreads();
  for (int st = 128; st > 0; st >>= 1) { if (tid < st) red[tid] += red[tid + st]; __syncthreads(); }
  if (tid == 0) bag_ws[b] = has ? red[0] : 0.0f;
}

__global__ void loss_kernel(const float* __restrict__ bag_ws, const float* __restrict__ labels,
                            float* __restrict__ out) {
  if (threadIdx.x == 0 && blockIdx.x == 0) {
    float t = 0;
    for (int b = 0; b < BCH; ++b) {
      float x = bag_ws[b];
      float sp = fmaxf(x, 0.0f) + log1pf(expf(-fabsf(x)));
      t += sp - x * labels[b];
    }
    out[0] = t / (float)BCH;
  }
}

extern "C" void kernel_launch(void* const* d_in, const int* in_sizes, int n_in,
                              void* d_out, int out_size, void* d_ws, size_t ws_size,
                              hipStream_t stream) {
  (void)in_sizes; (void)n_in; (void)out_size; (void)ws_size;
  const float* state = (const float*)d_in[0];
  const float* trig  = (const float*)d_in[1];
  const float* gnn   = (const float*)d_in[2];
  const int*   zone  = (const int*)d_in[3];
  const int*   cats  = (const int*)d_in[4];
  const float* labels = (const float*)d_in[5];
  const float* s2t_qkv_w = (const float*)d_in[6];
  const float* s2t_qkv_b = (const float*)d_in[7];
  const float* s2t_out_w = (const float*)d_in[8];
  const float* s2t_out_b = (const float*)d_in[9];
  const float* t2s_qkv_w = (const float*)d_in[10];
  const float* t2s_qkv_b = (const float*)d_in[11];
  const float* t2s_out_w = (const float*)d_in[12];
  const float* t2s_out_b = (const float*)d_in[13];
  const float* fconv1_w = (const float*)d_in[14];
  const float* fbn1_g = (const float*)d_in[15];
  const float* fbn1_b = (const float*)d_in[16];
  const float* fconv2_w = (const float*)d_in[17];
  const float* fbn2_g = (const float*)d_in[18];
  const float* fbn2_b = (const float*)d_in[19];
  const float* outc_w = (const float*)d_in[20];
  const float* outc_b = (const float*)d_in[21];
  const float* attn1_w = (const float*)d_in[22];
  const float* attn1_b = (const float*)d_in[23];
  const float* attn2_w = (const float*)d_in[24];
  const float* attn2_b = (const float*)d_in[25];

  float* ws = (float*)d_ws;
  const size_t NBP = (size_t)BCH * L * 128; // 1,048,576
  size_t o = 0;
  float* c1 = ws + o; o += NBP;            // conv1 out (pm f32); c1||c2 alias poS during attn
  float* c2 = ws + o; o += NBP;            // conv2 out (cm f32)
  float* stats = ws + o; o += 512;         // mean1 rstd1 mean2 rstd2
  float* score = ws + o; o += (size_t)BCH * L;
  float* plog = ws + o; o += (size_t)BCH * L;
  float* bag = ws + o; o += 8;
  short* Xs = (short*)(ws + o); o += NBP / 2;
  short* Xt = (short*)(ws + o); o += NBP / 2;
  short* qsb = (short*)(ws + o); o += NBP / 2;
  short* ksb = (short*)(ws + o); o += NBP / 2;   // head-packed K
  short* qtb = (short*)(ws + o); o += NBP / 2;
  short* ktb = (short*)(ws + o); o += NBP / 2;   // head-packed K
  short* vTsb = (short*)(ws + o); o += NBP / 2;
  short* vTtb = (short*)(ws + o); o += NBP / 2;
  short* fusedPM = (short*)(ws + o); o += (size_t)BCH * L * CPAD / 2;
  short* X2 = (short*)(ws + o); o += NBP / 2;
  short* W1b = (short*)(ws + o); o += (9 * 128 * CPAD) / 2;
  short* W2b = (short*)(ws + o); o += (9 * 128 * 128) / 2;
  short* wSb = (short*)(ws + o); o += 24576;
  short* wTb = (short*)(ws + o); o += 24576;
  short* woSb = (short*)(ws + o); o += 8192;
  short* woTb = (short*)(ws + o); o += 8192;
  short* poT = (short*)(ws + o); o += 2 * NBP;   // 4 splits x 2^20 bf16 (8 MB), dedicated
  float* psum1 = ws + o; o += 128 * 512;
  float* psq1 = ws + o; o += 128 * 512;
  float* psum2 = ws + o; o += 128 * 512;
  float* psq2 = ws + o; o += 128 * 512;
  float* pmT2 = ws + o; o += 4 * 32768;          // pm/pl for T kept out of fusedPM
  float* plT2 = ws + o; o += 4 * 32768;

  // attention partial buffers aliased onto regions dead during attention
  short* poS = (short*)c1;            // c1||c2 contiguous: 8 MB = 4 splits x 2^20 bf16
  // pm/pl for S live in X2 (dead until bnapply): 8 x 131072 f32 = 1 MB << 2 MB X2
  float* pmS = (float*)X2;
  float* plS = pmS + 131072;
  float* pmT = pmT2;
  float* plT = plT2;

  prep_fused<<<4112, 256, 0, stream>>>(fconv1_w, fconv2_w, s2t_qkv_w, t2s_qkv_w,
                                       s2t_out_w, t2s_out_w, state, trig,
                                       W1b, W2b, wSb, wTb, woSb, woTb, Xs, Xt);

  gemm_qkv<<<dim3(128, 6), 256, 0, stream>>>(Xs, Xt, wSb, wTb, s2t_qkv_b, t2s_qkv_b,
                                             qsb, ksb, qtb, ktb, vTsb, vTtb);

  flash_attn6<<<dim3(16, NHEAD, 16), 256, 0, stream>>>(qsb, ksb, vTsb, qtb, ktb, vTtb,
                                                       poS, poT, pmS, plS, pmT, plT);

  gemm_o<<<dim3(128, 2), 256, 0, stream>>>(poS, pmS, plS, poT, pmT, plT,
                                           woSb, woTb, s2t_out_b, t2s_out_b,
                                           gnn, fusedPM);

  conv1_mfma<<<dim3(256, 4), 128, 0, stream>>>(fusedPM, W1b, c1, psum1, psq1);
  stats_reduce<<<128, 256, 0, stream>>>(psum1, psq1, stats, stats + 128);
  bnapply_pm<<<4096, 256, 0, stream>>>(c1, stats, stats + 128, fbn1_g, fbn1_b, X2);

  conv2_mfma<<<dim3(256, 4), 128, 0, stream>>>(X2, W2b, c2, psum2, psq2);
  stats_reduce<<<128, 256, 0, stream>>>(psum2, psq2, stats + 256, stats + 384);

  head_kernel<<<BCH * 64, 256, 0, stream>>>(c2, stats + 256, stats + 384, fbn2_g, fbn2_b,
                                            attn1_w, attn1_b, attn2_w, attn2_b,
                                            outc_w, outc_b, score, plog);

  finalize_kernel<<<BCH, 256, 0, stream>>>(score, plog, zone, cats, (float*)d_out + 1, bag);
  loss_kernel<<<1, 64, 0, stream>>>(bag, labels, (float*)d_out);
}